// Round 3
// baseline (2914.517 us; speedup 1.0000x reference)
//
#include <hip/hip_runtime.h>
#include <hip/hip_bf16.h>

#define TK 4096   // tokens
#define DD 2048   // hidden
#define FF 4096   // intermediate
#define NE 8      // experts
#define BM 128
#define BN 128
#define BK 32

typedef __attribute__((ext_vector_type(8))) short bf16x8;
typedef __attribute__((ext_vector_type(4))) short bf16x4;
typedef __attribute__((ext_vector_type(4))) float f32x4;

__device__ __forceinline__ unsigned short f2bf(float f) {
  return __builtin_bit_cast(unsigned short, __float2bfloat16(f));  // v_cvt_pk_bf16_f32
}

// LDS tiles: [row][32 bf16] = 64B rows, 4 x 16B slots/row.
// Bank-quad of a 16B granule = ((row&1)<<2) | physslot.
// physslot = slot ^ g(row); g bijective on row bits[2:1], XOR bits[4:3]:
// verified conflict-free (<=2-way) for A-write, B-write(perm'd), frag reads.
__device__ __forceinline__ int g_swz(int row) { return ((row >> 1) & 3) ^ ((row >> 3) & 3); }
__device__ __forceinline__ int swzoff(int row, int bir) {
  return row * 64 + ((((bir >> 4) ^ g_swz(row)) & 3) << 4) + (bir & 15);
}
// physical-row permutation for B tiles: writers (rows 4*fblk+j) land on
// consecutive physical rows across lanes; applied on write AND read.
__device__ __forceinline__ int permB(int f) {
  return (f & 0x60) | ((f & 3) << 3) | ((f >> 2) & 7);
}

// ---------------- router: 1 wave per token ----------------
__global__ void k_router(const float* __restrict__ x, const float* __restrict__ gw,
                         int* __restrict__ cnt, int* __restrict__ ltok,
                         float* __restrict__ lw) {
  int tok = (blockIdx.x * blockDim.x + threadIdx.x) >> 6;
  int lane = threadIdx.x & 63;
  if (tok >= TK) return;
  const float* xr = x + (size_t)tok * DD;
  float a0=0,a1=0,a2=0,a3=0,a4=0,a5=0,a6=0,a7=0;
  for (int p = 0; p < DD / 256; ++p) {
    int d0 = p * 256 + lane * 4;
    f32x4 xv = *(const f32x4*)(xr + d0);
#pragma unroll
    for (int j = 0; j < 4; ++j) {
      float xs = xv[j];
      const f32x4* g = (const f32x4*)(gw + (size_t)(d0 + j) * NE);
      f32x4 g0 = g[0], g1 = g[1];
      a0 += xs * g0[0]; a1 += xs * g0[1]; a2 += xs * g0[2]; a3 += xs * g0[3];
      a4 += xs * g1[0]; a5 += xs * g1[1]; a6 += xs * g1[2]; a7 += xs * g1[3];
    }
  }
#pragma unroll
  for (int s = 32; s > 0; s >>= 1) {
    a0 += __shfl_xor(a0, s, 64); a1 += __shfl_xor(a1, s, 64);
    a2 += __shfl_xor(a2, s, 64); a3 += __shfl_xor(a3, s, 64);
    a4 += __shfl_xor(a4, s, 64); a5 += __shfl_xor(a5, s, 64);
    a6 += __shfl_xor(a6, s, 64); a7 += __shfl_xor(a7, s, 64);
  }
  if (lane == 0) {
    float p_[NE] = {a0, a1, a2, a3, a4, a5, a6, a7};
    float m = p_[0];
#pragma unroll
    for (int e = 1; e < NE; ++e) m = fmaxf(m, p_[e]);
    float ssum = 0.f;
#pragma unroll
    for (int e = 0; e < NE; ++e) { p_[e] = __expf(p_[e] - m); ssum += p_[e]; }
    float inv = 1.f / ssum;
    int i1 = 0; float b1 = p_[0];
#pragma unroll
    for (int e = 1; e < NE; ++e) if (p_[e] > b1) { b1 = p_[e]; i1 = e; }
    int i2 = -1; float b2 = -1.f;
#pragma unroll
    for (int e = 0; e < NE; ++e) if (e != i1 && p_[e] > b2) { b2 = p_[e]; i2 = e; }
    int s1 = atomicAdd(&cnt[i1], 1);
    ltok[i1 * TK + s1] = tok; lw[i1 * TK + s1] = b1 * inv;
    int s2 = atomicAdd(&cnt[i2], 1);
    ltok[i2 * TK + s2] = tok; lw[i2 * TK + s2] = b2 * inv;
  }
}

__global__ void k_prefix(const int* __restrict__ cnt, int* __restrict__ off) {
  if (threadIdx.x == 0) {
    int a = 0;
#pragma unroll
    for (int e = 0; e < NE; ++e) { off[e] = a; a += cnt[e]; }
    off[NE] = a;
  }
}

// ---------------- GEMM1: H = silu(X W1) * (X W3) * w  (bf16 out) ----------------
__global__ __launch_bounds__(256, 3)
void k_gemm1(const float* __restrict__ x, const float* __restrict__ w1g,
             const float* __restrict__ w3g, const int* __restrict__ cnt,
             const int* __restrict__ off, const int* __restrict__ ltok,
             const float* __restrict__ lw, unsigned short* __restrict__ H) {
  const int e = blockIdx.z;
  const int ce = cnt[e];
  const int m0 = blockIdx.y * BM;
  if (m0 >= ce) return;
  const int n0 = blockIdx.x * BN;
  const int tid = threadIdx.x, lane = tid & 63, wv = tid >> 6;
  const int wr = wv >> 1, wc = wv & 1;
  const float* W1 = w1g + (size_t)e * DD * FF;
  const float* W3 = w3g + (size_t)e * DD * FF;
  const int base = off[e];

  __shared__ unsigned short As[2][BM * BK];
  __shared__ unsigned short B1s[2][BN * BK];
  __shared__ unsigned short B3s[2][BN * BK];

  const int arow = tid >> 1, ah = tid & 1;
  const float* xrow = (m0 + arow < ce) ? (x + (size_t)ltok[e * TK + (m0 + arow)] * DD) : nullptr;
  const int dblk = tid >> 5, fblk = tid & 31;

  // loop-invariant LDS byte offsets
  const int kb = (lane >> 4) * 16;
  int aOff[4], bOff[4], wAoff[4], wBoff[4];
#pragma unroll
  for (int m = 0; m < 4; ++m) aOff[m] = swzoff(wr * 64 + m * 16 + (lane & 15), kb);
#pragma unroll
  for (int n = 0; n < 4; ++n) bOff[n] = swzoff(permB(wc * 64 + n * 16 + (lane & 15)), kb);
#pragma unroll
  for (int j = 0; j < 4; ++j) {
    wAoff[j] = swzoff(arow, ah * 32 + j * 8);
    wBoff[j] = swzoff(permB(fblk * 4 + j), dblk * 8);
  }

  f32x4 acc1[4][4], acc3[4][4];
#pragma unroll
  for (int m = 0; m < 4; ++m)
#pragma unroll
    for (int n = 0; n < 4; ++n)
#pragma unroll
      for (int j = 0; j < 4; ++j) { acc1[m][n][j] = 0.f; acc3[m][n][j] = 0.f; }

  f32x4 av[4], v1[4], v3[4];

  auto LOAD = [&](int kt) {
    const int k0 = kt * BK;
#pragma unroll
    for (int j = 0; j < 4; ++j) {
      if (xrow) av[j] = *(const f32x4*)(xrow + k0 + ah * 16 + j * 4);
      else { av[j][0] = 0.f; av[j][1] = 0.f; av[j][2] = 0.f; av[j][3] = 0.f; }
    }
    const float* p1 = W1 + (size_t)(k0 + dblk * 4) * FF + (n0 + fblk * 4);
    const float* p3 = W3 + (size_t)(k0 + dblk * 4) * FF + (n0 + fblk * 4);
#pragma unroll
    for (int r = 0; r < 4; ++r) {
      v1[r] = *(const f32x4*)(p1 + (size_t)r * FF);
      v3[r] = *(const f32x4*)(p3 + (size_t)r * FF);
    }
  };
  auto STORE = [&](int buf) {
#pragma unroll
    for (int j = 0; j < 4; ++j) {
      bf16x4 t;
      t[0] = (short)f2bf(av[j][0]); t[1] = (short)f2bf(av[j][1]);
      t[2] = (short)f2bf(av[j][2]); t[3] = (short)f2bf(av[j][3]);
      *(bf16x4*)((char*)As[buf] + wAoff[j]) = t;
    }
#pragma unroll
    for (int j = 0; j < 4; ++j) {   // transpose 4x4: col j of the block
      bf16x4 t1, t3;
      t1[0] = (short)f2bf(v1[0][j]); t1[1] = (short)f2bf(v1[1][j]);
      t1[2] = (short)f2bf(v1[2][j]); t1[3] = (short)f2bf(v1[3][j]);
      t3[0] = (short)f2bf(v3[0][j]); t3[1] = (short)f2bf(v3[1][j]);
      t3[2] = (short)f2bf(v3[2][j]); t3[3] = (short)f2bf(v3[3][j]);
      *(bf16x4*)((char*)B1s[buf] + wBoff[j]) = t1;
      *(bf16x4*)((char*)B3s[buf] + wBoff[j]) = t3;
    }
  };

  LOAD(0);
  STORE(0);
  int cur = 0;
  const int NT = DD / BK;
  for (int kt = 0; kt < NT; ++kt) {
    if (kt + 1 < NT) LOAD(kt + 1);
    __syncthreads();
    bf16x8 af[4];
#pragma unroll
    for (int m = 0; m < 4; ++m) af[m] = *(const bf16x8*)((const char*)As[cur] + aOff[m]);
#pragma unroll
    for (int n = 0; n < 4; ++n) {
      bf16x8 b1 = *(const bf16x8*)((const char*)B1s[cur] + bOff[n]);
      bf16x8 b3 = *(const bf16x8*)((const char*)B3s[cur] + bOff[n]);
#pragma unroll
      for (int m = 0; m < 4; ++m) {
        acc1[m][n] = __builtin_amdgcn_mfma_f32_16x16x32_bf16(af[m], b1, acc1[m][n], 0, 0, 0);
        acc3[m][n] = __builtin_amdgcn_mfma_f32_16x16x32_bf16(af[m], b3, acc3[m][n], 0, 0, 0);
      }
    }
    if (kt + 1 < NT) STORE(cur ^ 1);
    cur ^= 1;
  }

  // epilogue: silu(acc1)*acc3*combine_weight -> H (bf16)
#pragma unroll
  for (int m = 0; m < 4; ++m) {
    const int rbase = wr * 64 + m * 16 + ((lane >> 4) << 2);
    float wts[4]; bool val[4];
#pragma unroll
    for (int j = 0; j < 4; ++j) {
      int r = m0 + rbase + j;
      val[j] = r < ce;
      wts[j] = val[j] ? lw[e * TK + r] : 0.f;
    }
#pragma unroll
    for (int n = 0; n < 4; ++n) {
      const int col = n0 + wc * 64 + n * 16 + (lane & 15);
#pragma unroll
      for (int j = 0; j < 4; ++j) {
        if (!val[j]) continue;
        float s1 = acc1[m][n][j], s3 = acc3[m][n][j];
        float h = s1 / (1.f + __expf(-s1)) * s3 * wts[j];
        H[(size_t)(base + m0 + rbase + j) * FF + col] = f2bf(h);
      }
    }
  }
}

// ---------------- GEMM2: out += H W2 (scatter by token, fp32 atomics) ----------------
__global__ __launch_bounds__(256, 3)
void k_gemm2(const unsigned short* __restrict__ H, const float* __restrict__ w2g,
             const int* __restrict__ cnt, const int* __restrict__ off,
             const int* __restrict__ ltok, float* __restrict__ out) {
  const int e = blockIdx.z;
  const int ce = cnt[e];
  const int m0 = blockIdx.y * BM;
  if (m0 >= ce) return;
  const int n0 = blockIdx.x * BN;
  const int tid = threadIdx.x, lane = tid & 63, wv = tid >> 6;
  const int wr = wv >> 1, wc = wv & 1;
  const float* W2 = w2g + (size_t)e * FF * DD;
  const int base = off[e];

  __shared__ unsigned short As[2][BM * BK];
  __shared__ unsigned short Bs[2][BN * BK];

  const int arow = tid >> 1, ah = tid & 1;
  const bool aval = (m0 + arow) < ce;
  const unsigned short* hrow = H + (size_t)(base + m0 + arow) * FF;
  const int kblk = tid >> 5, nblk = tid & 31;

  const int kb = (lane >> 4) * 16;
  int aOff[4], bOff[4], wAoff[2], wBoff[4];
#pragma unroll
  for (int m = 0; m < 4; ++m) aOff[m] = swzoff(wr * 64 + m * 16 + (lane & 15), kb);
#pragma unroll
  for (int n = 0; n < 4; ++n) bOff[n] = swzoff(permB(wc * 64 + n * 16 + (lane & 15)), kb);
#pragma unroll
  for (int j = 0; j < 2; ++j) wAoff[j] = swzoff(arow, ah * 32 + j * 16);
#pragma unroll
  for (int j = 0; j < 4; ++j) wBoff[j] = swzoff(permB(nblk * 4 + j), kblk * 8);

  f32x4 acc[4][4];
#pragma unroll
  for (int m = 0; m < 4; ++m)
#pragma unroll
    for (int n = 0; n < 4; ++n)
#pragma unroll
      for (int j = 0; j < 4; ++j) acc[m][n][j] = 0.f;

  bf16x8 av2[2];
  f32x4 wv2[4];

  auto LOAD = [&](int kt) {
    const int k0 = kt * BK;
#pragma unroll
    for (int j = 0; j < 2; ++j) {
      if (aval) av2[j] = *(const bf16x8*)(hrow + k0 + ah * 16 + j * 8);
      else {
#pragma unroll
        for (int q = 0; q < 8; ++q) av2[j][q] = 0;
      }
    }
    const float* p = W2 + (size_t)(k0 + kblk * 4) * DD + (n0 + nblk * 4);
#pragma unroll
    for (int r = 0; r < 4; ++r) wv2[r] = *(const f32x4*)(p + (size_t)r * DD);
  };
  auto STORE = [&](int buf) {
#pragma unroll
    for (int j = 0; j < 2; ++j) *(bf16x8*)((char*)As[buf] + wAoff[j]) = av2[j];
#pragma unroll
    for (int j = 0; j < 4; ++j) {
      bf16x4 t;
      t[0] = (short)f2bf(wv2[0][j]); t[1] = (short)f2bf(wv2[1][j]);
      t[2] = (short)f2bf(wv2[2][j]); t[3] = (short)f2bf(wv2[3][j]);
      *(bf16x4*)((char*)Bs[buf] + wBoff[j]) = t;
    }
  };

  LOAD(0);
  STORE(0);
  int cur = 0;
  const int NT = FF / BK;
  for (int kt = 0; kt < NT; ++kt) {
    if (kt + 1 < NT) LOAD(kt + 1);
    __syncthreads();
    bf16x8 af[4];
#pragma unroll
    for (int m = 0; m < 4; ++m) af[m] = *(const bf16x8*)((const char*)As[cur] + aOff[m]);
#pragma unroll
    for (int n = 0; n < 4; ++n) {
      bf16x8 bf = *(const bf16x8*)((const char*)Bs[cur] + bOff[n]);
#pragma unroll
      for (int m = 0; m < 4; ++m)
        acc[m][n] = __builtin_amdgcn_mfma_f32_16x16x32_bf16(af[m], bf, acc[m][n], 0, 0, 0);
    }
    if (kt + 1 < NT) STORE(cur ^ 1);
    cur ^= 1;
  }

#pragma unroll
  for (int m = 0; m < 4; ++m) {
    const int rbase = wr * 64 + m * 16 + ((lane >> 4) << 2);
    int toks[4]; bool val[4];
#pragma unroll
    for (int j = 0; j < 4; ++j) {
      int r = m0 + rbase + j;
      val[j] = r < ce;
      toks[j] = val[j] ? ltok[e * TK + r] : 0;
    }
#pragma unroll
    for (int n = 0; n < 4; ++n) {
      const int col = n0 + wc * 64 + n * 16 + (lane & 15);
#pragma unroll
      for (int j = 0; j < 4; ++j)
        if (val[j]) atomicAdd(out + (size_t)toks[j] * DD + col, acc[m][n][j]);
    }
  }
}

extern "C" void kernel_launch(void* const* d_in, const int* in_sizes, int n_in,
                              void* d_out, int out_size, void* d_ws, size_t ws_size,
                              hipStream_t stream) {
  const float* x  = (const float*)d_in[0];
  const float* gw = (const float*)d_in[1];
  const float* w1 = (const float*)d_in[2];
  const float* w3 = (const float*)d_in[3];
  const float* w2 = (const float*)d_in[4];
  float* out = (float*)d_out;

  char* ws = (char*)d_ws;
  int*   cnt  = (int*)(ws);
  int*   off  = (int*)(ws + 64);
  int*   ltok = (int*)(ws + 256);
  float* lw   = (float*)(ws + 256 + (size_t)NE * TK * 4);
  unsigned short* H = (unsigned short*)(ws + (1 << 20));
  const size_t need = (1u << 20) + (size_t)2 * TK * FF * 2;  // ~68 MB
  if (ws_size < need) return;

  hipMemsetAsync(cnt, 0, 64, stream);
  hipMemsetAsync(d_out, 0, (size_t)out_size * 4, stream);
  k_router<<<dim3(TK / 4), 256, 0, stream>>>(x, gw, cnt, ltok, lw);
  k_prefix<<<dim3(1), 64, 0, stream>>>(cnt, off);
  k_gemm1<<<dim3(FF / BN, TK / BM, NE), 256, 0, stream>>>(x, w1, w3, cnt, off, ltok, lw, H);
  k_gemm2<<<dim3(DD / BN, TK / BM, NE), 256, 0, stream>>>(H, w2, cnt, off, ltok, out);
}

// Round 4
// 981.651 us; speedup vs baseline: 2.9690x; 2.9690x over previous
//
#include <hip/hip_runtime.h>
#include <hip/hip_bf16.h>

#define TK 4096   // tokens
#define DD 2048   // hidden
#define FF 4096   // intermediate
#define NE 8      // experts
#define BM 128
#define BN 128
#define BK 32

typedef __attribute__((ext_vector_type(8))) short bf16x8;
typedef __attribute__((ext_vector_type(4))) short bf16x4;
typedef __attribute__((ext_vector_type(4))) float f32x4;

__device__ __forceinline__ unsigned short f2bf(float f) {
  return __builtin_bit_cast(unsigned short, __float2bfloat16(f));  // v_cvt_pk_bf16_f32
}

// LDS tiles: [row][32 bf16] = 64B rows, 4 x 16B slots/row.
// Bank-quad of a 16B granule = ((row&1)<<2) | physslot.
// physslot = slot ^ g(row); g bijective on row bits[2:1], XOR bits[4:3]:
// verified conflict-free (<=2-way) for A-write, B-write(perm'd), frag reads.
__device__ __forceinline__ int g_swz(int row) { return ((row >> 1) & 3) ^ ((row >> 3) & 3); }
__device__ __forceinline__ int swzoff(int row, int bir) {
  return row * 64 + ((((bir >> 4) ^ g_swz(row)) & 3) << 4) + (bir & 15);
}
// physical-row permutation for B tiles: writers (rows 4*fblk+j) land on
// consecutive physical rows across lanes; applied on write AND read.
__device__ __forceinline__ int permB(int f) {
  return (f & 0x60) | ((f & 3) << 3) | ((f >> 2) & 7);
}

// ---------------- router: 1 wave per token ----------------
__global__ void k_router(const float* __restrict__ x, const float* __restrict__ gw,
                         int* __restrict__ cnt, int* __restrict__ ltok,
                         float* __restrict__ lw) {
  int tok = (blockIdx.x * blockDim.x + threadIdx.x) >> 6;
  int lane = threadIdx.x & 63;
  if (tok >= TK) return;
  const float* xr = x + (size_t)tok * DD;
  float a0=0,a1=0,a2=0,a3=0,a4=0,a5=0,a6=0,a7=0;
  for (int p = 0; p < DD / 256; ++p) {
    int d0 = p * 256 + lane * 4;
    f32x4 xv = *(const f32x4*)(xr + d0);
#pragma unroll
    for (int j = 0; j < 4; ++j) {
      float xs = xv[j];
      const f32x4* g = (const f32x4*)(gw + (size_t)(d0 + j) * NE);
      f32x4 g0 = g[0], g1 = g[1];
      a0 += xs * g0[0]; a1 += xs * g0[1]; a2 += xs * g0[2]; a3 += xs * g0[3];
      a4 += xs * g1[0]; a5 += xs * g1[1]; a6 += xs * g1[2]; a7 += xs * g1[3];
    }
  }
#pragma unroll
  for (int s = 32; s > 0; s >>= 1) {
    a0 += __shfl_xor(a0, s, 64); a1 += __shfl_xor(a1, s, 64);
    a2 += __shfl_xor(a2, s, 64); a3 += __shfl_xor(a3, s, 64);
    a4 += __shfl_xor(a4, s, 64); a5 += __shfl_xor(a5, s, 64);
    a6 += __shfl_xor(a6, s, 64); a7 += __shfl_xor(a7, s, 64);
  }
  if (lane == 0) {
    float p_[NE] = {a0, a1, a2, a3, a4, a5, a6, a7};
    float m = p_[0];
#pragma unroll
    for (int e = 1; e < NE; ++e) m = fmaxf(m, p_[e]);
    float ssum = 0.f;
#pragma unroll
    for (int e = 0; e < NE; ++e) { p_[e] = __expf(p_[e] - m); ssum += p_[e]; }
    float inv = 1.f / ssum;
    int i1 = 0; float b1 = p_[0];
#pragma unroll
    for (int e = 1; e < NE; ++e) if (p_[e] > b1) { b1 = p_[e]; i1 = e; }
    int i2 = -1; float b2 = -1.f;
#pragma unroll
    for (int e = 0; e < NE; ++e) if (e != i1 && p_[e] > b2) { b2 = p_[e]; i2 = e; }
    int s1 = atomicAdd(&cnt[i1], 1);
    ltok[i1 * TK + s1] = tok; lw[i1 * TK + s1] = b1 * inv;
    int s2 = atomicAdd(&cnt[i2], 1);
    ltok[i2 * TK + s2] = tok; lw[i2 * TK + s2] = b2 * inv;
  }
}

__global__ void k_prefix(const int* __restrict__ cnt, int* __restrict__ off) {
  if (threadIdx.x == 0) {
    int a = 0;
#pragma unroll
    for (int e = 0; e < NE; ++e) { off[e] = a; a += cnt[e]; }
    off[NE] = a;
  }
}

// ---------------- GEMM1: H = silu(X W1) * (X W3) * w  (bf16 out) ----------------
// NOTE: __launch_bounds__(256,2) is load-bearing. acc1+acc3 = 128 regs/thread;
// (256,3) caps the budget at ~170 and spills accumulators to scratch (round 3:
// 10.9 GB HBM traffic, 4.3x slower). 2 blocks/CU is the max for this tile.
__global__ __launch_bounds__(256, 2)
void k_gemm1(const float* __restrict__ x, const float* __restrict__ w1g,
             const float* __restrict__ w3g, const int* __restrict__ cnt,
             const int* __restrict__ off, const int* __restrict__ ltok,
             const float* __restrict__ lw, unsigned short* __restrict__ H) {
  const int e = blockIdx.z;
  const int ce = cnt[e];
  const int m0 = blockIdx.y * BM;
  if (m0 >= ce) return;
  const int n0 = blockIdx.x * BN;
  const int tid = threadIdx.x, lane = tid & 63, wv = tid >> 6;
  const int wr = wv >> 1, wc = wv & 1;
  const float* W1 = w1g + (size_t)e * DD * FF;
  const float* W3 = w3g + (size_t)e * DD * FF;
  const int base = off[e];

  __shared__ unsigned short As[2][BM * BK];
  __shared__ unsigned short B1s[2][BN * BK];
  __shared__ unsigned short B3s[2][BN * BK];

  const int arow = tid >> 1, ah = tid & 1;
  const float* xrow = (m0 + arow < ce) ? (x + (size_t)ltok[e * TK + (m0 + arow)] * DD) : nullptr;
  const int dblk = tid >> 5, fblk = tid & 31;

  // loop-invariant LDS byte offsets
  const int kb = (lane >> 4) * 16;
  int aOff[4], bOff[4], wAoff[4], wBoff[4];
#pragma unroll
  for (int m = 0; m < 4; ++m) aOff[m] = swzoff(wr * 64 + m * 16 + (lane & 15), kb);
#pragma unroll
  for (int n = 0; n < 4; ++n) bOff[n] = swzoff(permB(wc * 64 + n * 16 + (lane & 15)), kb);
#pragma unroll
  for (int j = 0; j < 4; ++j) {
    wAoff[j] = swzoff(arow, ah * 32 + j * 8);
    wBoff[j] = swzoff(permB(fblk * 4 + j), dblk * 8);
  }

  f32x4 acc1[4][4], acc3[4][4];
#pragma unroll
  for (int m = 0; m < 4; ++m)
#pragma unroll
    for (int n = 0; n < 4; ++n)
#pragma unroll
      for (int j = 0; j < 4; ++j) { acc1[m][n][j] = 0.f; acc3[m][n][j] = 0.f; }

  f32x4 av[4], v1[4], v3[4];

  auto LOAD = [&](int kt) {
    const int k0 = kt * BK;
#pragma unroll
    for (int j = 0; j < 4; ++j) {
      if (xrow) av[j] = *(const f32x4*)(xrow + k0 + ah * 16 + j * 4);
      else { av[j][0] = 0.f; av[j][1] = 0.f; av[j][2] = 0.f; av[j][3] = 0.f; }
    }
    const float* p1 = W1 + (size_t)(k0 + dblk * 4) * FF + (n0 + fblk * 4);
    const float* p3 = W3 + (size_t)(k0 + dblk * 4) * FF + (n0 + fblk * 4);
#pragma unroll
    for (int r = 0; r < 4; ++r) {
      v1[r] = *(const f32x4*)(p1 + (size_t)r * FF);
      v3[r] = *(const f32x4*)(p3 + (size_t)r * FF);
    }
  };
  auto STORE = [&](int buf) {
#pragma unroll
    for (int j = 0; j < 4; ++j) {
      bf16x4 t;
      t[0] = (short)f2bf(av[j][0]); t[1] = (short)f2bf(av[j][1]);
      t[2] = (short)f2bf(av[j][2]); t[3] = (short)f2bf(av[j][3]);
      *(bf16x4*)((char*)As[buf] + wAoff[j]) = t;
    }
#pragma unroll
    for (int j = 0; j < 4; ++j) {   // transpose 4x4: col j of the block
      bf16x4 t1, t3;
      t1[0] = (short)f2bf(v1[0][j]); t1[1] = (short)f2bf(v1[1][j]);
      t1[2] = (short)f2bf(v1[2][j]); t1[3] = (short)f2bf(v1[3][j]);
      t3[0] = (short)f2bf(v3[0][j]); t3[1] = (short)f2bf(v3[1][j]);
      t3[2] = (short)f2bf(v3[2][j]); t3[3] = (short)f2bf(v3[3][j]);
      *(bf16x4*)((char*)B1s[buf] + wBoff[j]) = t1;
      *(bf16x4*)((char*)B3s[buf] + wBoff[j]) = t3;
    }
  };

  LOAD(0);
  STORE(0);
  int cur = 0;
  const int NT = DD / BK;
  for (int kt = 0; kt < NT; ++kt) {
    if (kt + 1 < NT) LOAD(kt + 1);
    __syncthreads();
    bf16x8 af[4];
#pragma unroll
    for (int m = 0; m < 4; ++m) af[m] = *(const bf16x8*)((const char*)As[cur] + aOff[m]);
#pragma unroll
    for (int n = 0; n < 4; ++n) {
      bf16x8 b1 = *(const bf16x8*)((const char*)B1s[cur] + bOff[n]);
      bf16x8 b3 = *(const bf16x8*)((const char*)B3s[cur] + bOff[n]);
#pragma unroll
      for (int m = 0; m < 4; ++m) {
        acc1[m][n] = __builtin_amdgcn_mfma_f32_16x16x32_bf16(af[m], b1, acc1[m][n], 0, 0, 0);
        acc3[m][n] = __builtin_amdgcn_mfma_f32_16x16x32_bf16(af[m], b3, acc3[m][n], 0, 0, 0);
      }
    }
    if (kt + 1 < NT) STORE(cur ^ 1);
    cur ^= 1;
  }

  // epilogue: silu(acc1)*acc3*combine_weight -> H (bf16)
#pragma unroll
  for (int m = 0; m < 4; ++m) {
    const int rbase = wr * 64 + m * 16 + ((lane >> 4) << 2);
    float wts[4]; bool val[4];
#pragma unroll
    for (int j = 0; j < 4; ++j) {
      int r = m0 + rbase + j;
      val[j] = r < ce;
      wts[j] = val[j] ? lw[e * TK + r] : 0.f;
    }
#pragma unroll
    for (int n = 0; n < 4; ++n) {
      const int col = n0 + wc * 64 + n * 16 + (lane & 15);
#pragma unroll
      for (int j = 0; j < 4; ++j) {
        if (!val[j]) continue;
        float s1 = acc1[m][n][j], s3 = acc3[m][n][j];
        float h = s1 / (1.f + __expf(-s1)) * s3 * wts[j];
        H[(size_t)(base + m0 + rbase + j) * FF + col] = f2bf(h);
      }
    }
  }
}

// ---------------- GEMM2: out += H W2 (scatter by token, fp32 atomics) ----------------
__global__ __launch_bounds__(256, 2)
void k_gemm2(const unsigned short* __restrict__ H, const float* __restrict__ w2g,
             const int* __restrict__ cnt, const int* __restrict__ off,
             const int* __restrict__ ltok, float* __restrict__ out) {
  const int e = blockIdx.z;
  const int ce = cnt[e];
  const int m0 = blockIdx.y * BM;
  if (m0 >= ce) return;
  const int n0 = blockIdx.x * BN;
  const int tid = threadIdx.x, lane = tid & 63, wv = tid >> 6;
  const int wr = wv >> 1, wc = wv & 1;
  const float* W2 = w2g + (size_t)e * FF * DD;
  const int base = off[e];

  __shared__ unsigned short As[2][BM * BK];
  __shared__ unsigned short Bs[2][BN * BK];

  const int arow = tid >> 1, ah = tid & 1;
  const bool aval = (m0 + arow) < ce;
  const unsigned short* hrow = H + (size_t)(base + m0 + arow) * FF;
  const int kblk = tid >> 5, nblk = tid & 31;

  const int kb = (lane >> 4) * 16;
  int aOff[4], bOff[4], wAoff[2], wBoff[4];
#pragma unroll
  for (int m = 0; m < 4; ++m) aOff[m] = swzoff(wr * 64 + m * 16 + (lane & 15), kb);
#pragma unroll
  for (int n = 0; n < 4; ++n) bOff[n] = swzoff(permB(wc * 64 + n * 16 + (lane & 15)), kb);
#pragma unroll
  for (int j = 0; j < 2; ++j) wAoff[j] = swzoff(arow, ah * 32 + j * 16);
#pragma unroll
  for (int j = 0; j < 4; ++j) wBoff[j] = swzoff(permB(nblk * 4 + j), kblk * 8);

  f32x4 acc[4][4];
#pragma unroll
  for (int m = 0; m < 4; ++m)
#pragma unroll
    for (int n = 0; n < 4; ++n)
#pragma unroll
      for (int j = 0; j < 4; ++j) acc[m][n][j] = 0.f;

  bf16x8 av2[2];
  f32x4 wv2[4];

  auto LOAD = [&](int kt) {
    const int k0 = kt * BK;
#pragma unroll
    for (int j = 0; j < 2; ++j) {
      if (aval) av2[j] = *(const bf16x8*)(hrow + k0 + ah * 16 + j * 8);
      else {
#pragma unroll
        for (int q = 0; q < 8; ++q) av2[j][q] = 0;
      }
    }
    const float* p = W2 + (size_t)(k0 + kblk * 4) * DD + (n0 + nblk * 4);
#pragma unroll
    for (int r = 0; r < 4; ++r) wv2[r] = *(const f32x4*)(p + (size_t)r * DD);
  };
  auto STORE = [&](int buf) {
#pragma unroll
    for (int j = 0; j < 2; ++j) *(bf16x8*)((char*)As[buf] + wAoff[j]) = av2[j];
#pragma unroll
    for (int j = 0; j < 4; ++j) {
      bf16x4 t;
      t[0] = (short)f2bf(wv2[0][j]); t[1] = (short)f2bf(wv2[1][j]);
      t[2] = (short)f2bf(wv2[2][j]); t[3] = (short)f2bf(wv2[3][j]);
      *(bf16x4*)((char*)Bs[buf] + wBoff[j]) = t;
    }
  };

  LOAD(0);
  STORE(0);
  int cur = 0;
  const int NT = FF / BK;
  for (int kt = 0; kt < NT; ++kt) {
    if (kt + 1 < NT) LOAD(kt + 1);
    __syncthreads();
    bf16x8 af[4];
#pragma unroll
    for (int m = 0; m < 4; ++m) af[m] = *(const bf16x8*)((const char*)As[cur] + aOff[m]);
#pragma unroll
    for (int n = 0; n < 4; ++n) {
      bf16x8 bf = *(const bf16x8*)((const char*)Bs[cur] + bOff[n]);
#pragma unroll
      for (int m = 0; m < 4; ++m)
        acc[m][n] = __builtin_amdgcn_mfma_f32_16x16x32_bf16(af[m], bf, acc[m][n], 0, 0, 0);
    }
    if (kt + 1 < NT) STORE(cur ^ 1);
    cur ^= 1;
  }

#pragma unroll
  for (int m = 0; m < 4; ++m) {
    const int rbase = wr * 64 + m * 16 + ((lane >> 4) << 2);
    int toks[4]; bool val[4];
#pragma unroll
    for (int j = 0; j < 4; ++j) {
      int r = m0 + rbase + j;
      val[j] = r < ce;
      toks[j] = val[j] ? ltok[e * TK + r] : 0;
    }
#pragma unroll
    for (int n = 0; n < 4; ++n) {
      const int col = n0 + wc * 64 + n * 16 + (lane & 15);
#pragma unroll
      for (int j = 0; j < 4; ++j)
        if (val[j]) atomicAdd(out + (size_t)toks[j] * DD + col, acc[m][n][j]);
    }
  }
}

extern "C" void kernel_launch(void* const* d_in, const int* in_sizes, int n_in,
                              void* d_out, int out_size, void* d_ws, size_t ws_size,
                              hipStream_t stream) {
  const float* x  = (const float*)d_in[0];
  const float* gw = (const float*)d_in[1];
  const float* w1 = (const float*)d_in[2];
  const float* w3 = (const float*)d_in[3];
  const float* w2 = (const float*)d_in[4];
  float* out = (float*)d_out;

  char* ws = (char*)d_ws;
  int*   cnt  = (int*)(ws);
  int*   off  = (int*)(ws + 64);
  int*   ltok = (int*)(ws + 256);
  float* lw   = (float*)(ws + 256 + (size_t)NE * TK * 4);
  unsigned short* H = (unsigned short*)(ws + (1 << 20));
  const size_t need = (1u << 20) + (size_t)2 * TK * FF * 2;  // ~68 MB
  if (ws_size < need) return;

  hipMemsetAsync(cnt, 0, 64, stream);
  hipMemsetAsync(d_out, 0, (size_t)out_size * 4, stream);
  k_router<<<dim3(TK / 4), 256, 0, stream>>>(x, gw, cnt, ltok, lw);
  k_prefix<<<dim3(1), 64, 0, stream>>>(cnt, off);
  k_gemm1<<<dim3(FF / BN, TK / BM, NE), 256, 0, stream>>>(x, w1, w3, cnt, off, ltok, lw, H);
  k_gemm2<<<dim3(DD / BN, TK / BM, NE), 256, 0, stream>>>(H, w2, cnt, off, ltok, out);
}

// Round 5
// 962.891 us; speedup vs baseline: 3.0268x; 1.0195x over previous
//
#include <hip/hip_runtime.h>
#include <hip/hip_bf16.h>

#define TK 4096   // tokens
#define DD 2048   // hidden
#define FF 4096   // intermediate
#define NE 8      // experts
#define BM 128
#define BN 128
#define BKR 32    // reg-staged fallback K-tile
#define BKG 64    // global_load_lds path K-tile

typedef __attribute__((ext_vector_type(8))) short bf16x8;
typedef __attribute__((ext_vector_type(4))) short bf16x4;
typedef __attribute__((ext_vector_type(4))) float f32x4;

__device__ __forceinline__ unsigned short f2bf(float f) {
  return __builtin_bit_cast(unsigned short, __float2bfloat16(f));  // v_cvt_pk_bf16_f32
}

// async global->LDS, 16B per lane. LDS dest must be wave-uniform base (HW adds lane*16).
__device__ __forceinline__ void gl16(const unsigned short* g, unsigned short* l) {
  __builtin_amdgcn_global_load_lds(
      (const __attribute__((address_space(1))) unsigned int*)g,
      (__attribute__((address_space(3))) unsigned int*)l, 16, 0, 0);
}

// ---- fallback-path swizzle helpers (round-4, [row][32bf16] 64B rows) ----
__device__ __forceinline__ int g_swz(int row) { return ((row >> 1) & 3) ^ ((row >> 3) & 3); }
__device__ __forceinline__ int swzoff(int row, int bir) {
  return row * 64 + ((((bir >> 4) ^ g_swz(row)) & 3) << 4) + (bir & 15);
}
__device__ __forceinline__ int permB(int f) {
  return (f & 0x60) | ((f & 3) << 3) | ((f >> 2) & 7);
}

// ---------------- router: 1 wave per token (also emits X in bf16) ----------------
__global__ void k_router(const float* __restrict__ x, const float* __restrict__ gw,
                         int* __restrict__ cnt, int* __restrict__ ltok,
                         float* __restrict__ lw, unsigned short* __restrict__ xb) {
  int tok = (blockIdx.x * blockDim.x + threadIdx.x) >> 6;
  int lane = threadIdx.x & 63;
  if (tok >= TK) return;
  const float* xr = x + (size_t)tok * DD;
  float a0=0,a1=0,a2=0,a3=0,a4=0,a5=0,a6=0,a7=0;
  for (int p = 0; p < DD / 256; ++p) {
    int d0 = p * 256 + lane * 4;
    f32x4 xv = *(const f32x4*)(xr + d0);
    if (xb) {
      bf16x4 t;
      t[0] = (short)f2bf(xv[0]); t[1] = (short)f2bf(xv[1]);
      t[2] = (short)f2bf(xv[2]); t[3] = (short)f2bf(xv[3]);
      *(bf16x4*)(xb + (size_t)tok * DD + d0) = t;
    }
#pragma unroll
    for (int j = 0; j < 4; ++j) {
      float xs = xv[j];
      const f32x4* g = (const f32x4*)(gw + (size_t)(d0 + j) * NE);
      f32x4 g0 = g[0], g1 = g[1];
      a0 += xs * g0[0]; a1 += xs * g0[1]; a2 += xs * g0[2]; a3 += xs * g0[3];
      a4 += xs * g1[0]; a5 += xs * g1[1]; a6 += xs * g1[2]; a7 += xs * g1[3];
    }
  }
#pragma unroll
  for (int s = 32; s > 0; s >>= 1) {
    a0 += __shfl_xor(a0, s, 64); a1 += __shfl_xor(a1, s, 64);
    a2 += __shfl_xor(a2, s, 64); a3 += __shfl_xor(a3, s, 64);
    a4 += __shfl_xor(a4, s, 64); a5 += __shfl_xor(a5, s, 64);
    a6 += __shfl_xor(a6, s, 64); a7 += __shfl_xor(a7, s, 64);
  }
  if (lane == 0) {
    float p_[NE] = {a0, a1, a2, a3, a4, a5, a6, a7};
    float m = p_[0];
#pragma unroll
    for (int e = 1; e < NE; ++e) m = fmaxf(m, p_[e]);
    float ssum = 0.f;
#pragma unroll
    for (int e = 0; e < NE; ++e) { p_[e] = __expf(p_[e] - m); ssum += p_[e]; }
    float inv = 1.f / ssum;
    int i1 = 0; float b1 = p_[0];
#pragma unroll
    for (int e = 1; e < NE; ++e) if (p_[e] > b1) { b1 = p_[e]; i1 = e; }
    int i2 = -1; float b2 = -1.f;
#pragma unroll
    for (int e = 0; e < NE; ++e) if (e != i1 && p_[e] > b2) { b2 = p_[e]; i2 = e; }
    int s1 = atomicAdd(&cnt[i1], 1);
    ltok[i1 * TK + s1] = tok; lw[i1 * TK + s1] = b1 * inv;
    int s2 = atomicAdd(&cnt[i2], 1);
    ltok[i2 * TK + s2] = tok; lw[i2 * TK + s2] = b2 * inv;
  }
}

__global__ void k_prefix(const int* __restrict__ cnt, int* __restrict__ off) {
  if (threadIdx.x == 0) {
    int a = 0;
#pragma unroll
    for (int e = 0; e < NE; ++e) { off[e] = a; a += cnt[e]; }
    off[NE] = a;
  }
}

// ---------------- transpose+convert: src fp32 [R][C] -> dst bf16 [C][R], per expert ----------------
__global__ void k_tr(const float* __restrict__ src0, unsigned short* __restrict__ dst0,
                     int R, int C) {
  const int e = blockIdx.z;
  const float* src = src0 + (size_t)e * R * C;
  unsigned short* dst = dst0 + (size_t)e * R * C;
  const int r0 = blockIdx.y * 64, c0 = blockIdx.x * 64;
  const int tid = threadIdx.x;
  __shared__ unsigned short t[64][66];
#pragma unroll
  for (int p = 0; p < 4; ++p) {
    int r = p * 16 + (tid >> 4);
    int c = (tid & 15) * 4;
    f32x4 v = *(const f32x4*)(src + (size_t)(r0 + r) * C + c0 + c);
#pragma unroll
    for (int j = 0; j < 4; ++j) t[c + j][r] = f2bf(v[j]);
  }
  __syncthreads();
#pragma unroll
  for (int p = 0; p < 2; ++p) {
    int c = p * 32 + (tid >> 3);
    int r = (tid & 7) * 8;
    bf16x8 o;
#pragma unroll
    for (int j = 0; j < 8; ++j) o[j] = (short)t[c][r + j];
    *(bf16x8*)(dst + (size_t)(c0 + c) * R + r0 + r) = o;
  }
}

// ================== global_load_lds GEMM path (all-bf16 operands) ==================
// LDS tile [128 rows][64 bf16] linear (128B rows, 8x16B slots). Physical slot s of
// row r holds logical chunk s^(r&7): staged via pre-swizzled per-lane SOURCE addr,
// read via the same XOR on the frag byte offset (rule #21 both-sides swizzle).

// ---------------- GEMM1: H = silu(X W1) * (X W3) * w ----------------
__global__ __launch_bounds__(256, 2)
void k_gemm1g(const unsigned short* __restrict__ xb, const unsigned short* __restrict__ w1t,
              const unsigned short* __restrict__ w3t, const int* __restrict__ cnt,
              const int* __restrict__ off, const int* __restrict__ ltok,
              const float* __restrict__ lw, unsigned short* __restrict__ H) {
  const int e = blockIdx.z;
  const int ce = cnt[e];
  const int m0 = blockIdx.y * BM;
  if (m0 >= ce) return;
  const int n0 = blockIdx.x * BN;
  const int tid = threadIdx.x, lane = tid & 63, w = tid >> 6;
  const int wr = w >> 1, wc = w & 1;
  const unsigned short* W1 = w1t + (size_t)e * FF * DD;  // [F][D]
  const unsigned short* W3 = w3t + (size_t)e * FF * DD;
  const int base = off[e];

  __shared__ __align__(16) unsigned short As[BM * BKG];
  __shared__ __align__(16) unsigned short B1s[BN * BKG];
  __shared__ __align__(16) unsigned short B3s[BN * BKG];

  // staging: wave w stages segments s=w*4+i (rows s*8..s*8+7, 8 lanes/row, 16B/lane)
  const int swz8 = ((lane & 7) ^ ((lane >> 3) & 7)) * 8;  // pre-swizzled source chunk
  const unsigned short* aSrc[4];
  const unsigned short* b1Src[4];
  const unsigned short* b3Src[4];
#pragma unroll
  for (int i = 0; i < 4; ++i) {
    int row = w * 32 + i * 8 + (lane >> 3);
    int gm = m0 + row;
    int tok = (gm < ce) ? ltok[e * TK + gm] : 0;  // clamp: garbage rows masked at store
    aSrc[i]  = xb + (size_t)tok * DD + swz8;
    b1Src[i] = W1 + (size_t)(n0 + row) * DD + swz8;
    b3Src[i] = W3 + (size_t)(n0 + row) * DD + swz8;
  }

  // frag-read byte offsets (read-side XOR of the same swizzle)
  int aOff[4][2], bOff[4][2];
#pragma unroll
  for (int m = 0; m < 4; ++m) {
    int row = wr * 64 + m * 16 + (lane & 15);
#pragma unroll
    for (int kk = 0; kk < 2; ++kk) {
      int c = kk * 4 + (lane >> 4);
      aOff[m][kk] = row * 128 + ((c ^ (row & 7)) << 4);
    }
  }
#pragma unroll
  for (int n = 0; n < 4; ++n) {
    int row = wc * 64 + n * 16 + (lane & 15);
#pragma unroll
    for (int kk = 0; kk < 2; ++kk) {
      int c = kk * 4 + (lane >> 4);
      bOff[n][kk] = row * 128 + ((c ^ (row & 7)) << 4);
    }
  }

  f32x4 acc1[4][4], acc3[4][4];
#pragma unroll
  for (int m = 0; m < 4; ++m)
#pragma unroll
    for (int n = 0; n < 4; ++n)
#pragma unroll
      for (int j = 0; j < 4; ++j) { acc1[m][n][j] = 0.f; acc3[m][n][j] = 0.f; }

  const int NT = DD / BKG;
  for (int kt = 0; kt < NT; ++kt) {
#pragma unroll
    for (int i = 0; i < 4; ++i) {
      const int seg = w * 4 + i;
      gl16(aSrc[i],  &As[seg * 512]);
      gl16(b1Src[i], &B1s[seg * 512]);
      gl16(b3Src[i], &B3s[seg * 512]);
      aSrc[i] += BKG; b1Src[i] += BKG; b3Src[i] += BKG;
    }
    __syncthreads();  // compiler drains vmcnt before barrier
#pragma unroll
    for (int kk = 0; kk < 2; ++kk) {
      bf16x8 af[4];
#pragma unroll
      for (int m = 0; m < 4; ++m) af[m] = *(const bf16x8*)((const char*)As + aOff[m][kk]);
#pragma unroll
      for (int n = 0; n < 4; ++n) {
        bf16x8 b1 = *(const bf16x8*)((const char*)B1s + bOff[n][kk]);
        bf16x8 b3 = *(const bf16x8*)((const char*)B3s + bOff[n][kk]);
#pragma unroll
        for (int m = 0; m < 4; ++m) {
          acc1[m][n] = __builtin_amdgcn_mfma_f32_16x16x32_bf16(af[m], b1, acc1[m][n], 0, 0, 0);
          acc3[m][n] = __builtin_amdgcn_mfma_f32_16x16x32_bf16(af[m], b3, acc3[m][n], 0, 0, 0);
        }
      }
    }
    __syncthreads();  // reads done before next stage overwrites
  }

#pragma unroll
  for (int m = 0; m < 4; ++m) {
    const int rbase = wr * 64 + m * 16 + ((lane >> 4) << 2);
    float wts[4]; bool val[4];
#pragma unroll
    for (int j = 0; j < 4; ++j) {
      int r = m0 + rbase + j;
      val[j] = r < ce;
      wts[j] = val[j] ? lw[e * TK + r] : 0.f;
    }
#pragma unroll
    for (int n = 0; n < 4; ++n) {
      const int col = n0 + wc * 64 + n * 16 + (lane & 15);
#pragma unroll
      for (int j = 0; j < 4; ++j) {
        if (!val[j]) continue;
        float s1 = acc1[m][n][j], s3 = acc3[m][n][j];
        float h = s1 / (1.f + __expf(-s1)) * s3 * wts[j];
        H[(size_t)(base + m0 + rbase + j) * FF + col] = f2bf(h);
      }
    }
  }
}

// ---------------- GEMM2: out += H W2t (scatter by token, fp32 atomics) ----------------
__global__ __launch_bounds__(256, 3)
void k_gemm2g(const unsigned short* __restrict__ H, const unsigned short* __restrict__ w2t,
              const int* __restrict__ cnt, const int* __restrict__ off,
              const int* __restrict__ ltok, float* __restrict__ out) {
  const int e = blockIdx.z;
  const int ce = cnt[e];
  const int m0 = blockIdx.y * BM;
  if (m0 >= ce) return;
  const int n0 = blockIdx.x * BN;
  const int tid = threadIdx.x, lane = tid & 63, w = tid >> 6;
  const int wr = w >> 1, wc = w & 1;
  const unsigned short* W2 = w2t + (size_t)e * DD * FF;  // [D][F]
  const int base = off[e];

  __shared__ __align__(16) unsigned short As[BM * BKG];
  __shared__ __align__(16) unsigned short Bs[BN * BKG];

  const int swz8 = ((lane & 7) ^ ((lane >> 3) & 7)) * 8;
  const unsigned short* aSrc[4];
  const unsigned short* bSrc[4];
#pragma unroll
  for (int i = 0; i < 4; ++i) {
    int row = w * 32 + i * 8 + (lane >> 3);
    int gm = m0 + row;
    int hr = (gm < ce) ? gm : 0;
    aSrc[i] = H + (size_t)(base + hr) * FF + swz8;
    bSrc[i] = W2 + (size_t)(n0 + row) * FF + swz8;
  }

  int aOff[4][2], bOff[4][2];
#pragma unroll
  for (int m = 0; m < 4; ++m) {
    int row = wr * 64 + m * 16 + (lane & 15);
#pragma unroll
    for (int kk = 0; kk < 2; ++kk) {
      int c = kk * 4 + (lane >> 4);
      aOff[m][kk] = row * 128 + ((c ^ (row & 7)) << 4);
    }
  }
#pragma unroll
  for (int n = 0; n < 4; ++n) {
    int row = wc * 64 + n * 16 + (lane & 15);
#pragma unroll
    for (int kk = 0; kk < 2; ++kk) {
      int c = kk * 4 + (lane >> 4);
      bOff[n][kk] = row * 128 + ((c ^ (row & 7)) << 4);
    }
  }

  f32x4 acc[4][4];
#pragma unroll
  for (int m = 0; m < 4; ++m)
#pragma unroll
    for (int n = 0; n < 4; ++n)
#pragma unroll
      for (int j = 0; j < 4; ++j) acc[m][n][j] = 0.f;

  const int NT = FF / BKG;
  for (int kt = 0; kt < NT; ++kt) {
#pragma unroll
    for (int i = 0; i < 4; ++i) {
      const int seg = w * 4 + i;
      gl16(aSrc[i], &As[seg * 512]);
      gl16(bSrc[i], &Bs[seg * 512]);
      aSrc[i] += BKG; bSrc[i] += BKG;
    }
    __syncthreads();
#pragma unroll
    for (int kk = 0; kk < 2; ++kk) {
      bf16x8 af[4];
#pragma unroll
      for (int m = 0; m < 4; ++m) af[m] = *(const bf16x8*)((const char*)As + aOff[m][kk]);
#pragma unroll
      for (int n = 0; n < 4; ++n) {
        bf16x8 bf = *(const bf16x8*)((const char*)Bs + bOff[n][kk]);
#pragma unroll
        for (int m = 0; m < 4; ++m)
          acc[m][n] = __builtin_amdgcn_mfma_f32_16x16x32_bf16(af[m], bf, acc[m][n], 0, 0, 0);
      }
    }
    __syncthreads();
  }

#pragma unroll
  for (int m = 0; m < 4; ++m) {
    const int rbase = wr * 64 + m * 16 + ((lane >> 4) << 2);
    int toks[4]; bool val[4];
#pragma unroll
    for (int j = 0; j < 4; ++j) {
      int r = m0 + rbase + j;
      val[j] = r < ce;
      toks[j] = val[j] ? ltok[e * TK + r] : 0;
    }
#pragma unroll
    for (int n = 0; n < 4; ++n) {
      const int col = n0 + wc * 64 + n * 16 + (lane & 15);
#pragma unroll
      for (int j = 0; j < 4; ++j)
        if (val[j]) atomicAdd(out + (size_t)toks[j] * DD + col, acc[m][n][j]);
    }
  }
}

// ================== fallback reg-staged GEMMs (round-4, proven) ==================
__global__ __launch_bounds__(256, 2)
void k_gemm1(const float* __restrict__ x, const float* __restrict__ w1g,
             const float* __restrict__ w3g, const int* __restrict__ cnt,
             const int* __restrict__ off, const int* __restrict__ ltok,
             const float* __restrict__ lw, unsigned short* __restrict__ H) {
  const int e = blockIdx.z;
  const int ce = cnt[e];
  const int m0 = blockIdx.y * BM;
  if (m0 >= ce) return;
  const int n0 = blockIdx.x * BN;
  const int tid = threadIdx.x, lane = tid & 63, wv = tid >> 6;
  const int wr = wv >> 1, wc = wv & 1;
  const float* W1 = w1g + (size_t)e * DD * FF;
  const float* W3 = w3g + (size_t)e * DD * FF;
  const int base = off[e];

  __shared__ unsigned short As[2][BM * BKR];
  __shared__ unsigned short B1s[2][BN * BKR];
  __shared__ unsigned short B3s[2][BN * BKR];

  const int arow = tid >> 1, ah = tid & 1;
  const float* xrow = (m0 + arow < ce) ? (x + (size_t)ltok[e * TK + (m0 + arow)] * DD) : nullptr;
  const int dblk = tid >> 5, fblk = tid & 31;

  const int kb = (lane >> 4) * 16;
  int aOff[4], bOff[4], wAoff[4], wBoff[4];
#pragma unroll
  for (int m = 0; m < 4; ++m) aOff[m] = swzoff(wr * 64 + m * 16 + (lane & 15), kb);
#pragma unroll
  for (int n = 0; n < 4; ++n) bOff[n] = swzoff(permB(wc * 64 + n * 16 + (lane & 15)), kb);
#pragma unroll
  for (int j = 0; j < 4; ++j) {
    wAoff[j] = swzoff(arow, ah * 32 + j * 8);
    wBoff[j] = swzoff(permB(fblk * 4 + j), dblk * 8);
  }

  f32x4 acc1[4][4], acc3[4][4];
#pragma unroll
  for (int m = 0; m < 4; ++m)
#pragma unroll
    for (int n = 0; n < 4; ++n)
#pragma unroll
      for (int j = 0; j < 4; ++j) { acc1[m][n][j] = 0.f; acc3[m][n][j] = 0.f; }

  f32x4 av[4], v1[4], v3[4];

  auto LOAD = [&](int kt) {
    const int k0 = kt * BKR;
#pragma unroll
    for (int j = 0; j < 4; ++j) {
      if (xrow) av[j] = *(const f32x4*)(xrow + k0 + ah * 16 + j * 4);
      else { av[j][0] = 0.f; av[j][1] = 0.f; av[j][2] = 0.f; av[j][3] = 0.f; }
    }
    const float* p1 = W1 + (size_t)(k0 + dblk * 4) * FF + (n0 + fblk * 4);
    const float* p3 = W3 + (size_t)(k0 + dblk * 4) * FF + (n0 + fblk * 4);
#pragma unroll
    for (int r = 0; r < 4; ++r) {
      v1[r] = *(const f32x4*)(p1 + (size_t)r * FF);
      v3[r] = *(const f32x4*)(p3 + (size_t)r * FF);
    }
  };
  auto STORE = [&](int buf) {
#pragma unroll
    for (int j = 0; j < 4; ++j) {
      bf16x4 t;
      t[0] = (short)f2bf(av[j][0]); t[1] = (short)f2bf(av[j][1]);
      t[2] = (short)f2bf(av[j][2]); t[3] = (short)f2bf(av[j][3]);
      *(bf16x4*)((char*)As[buf] + wAoff[j]) = t;
    }
#pragma unroll
    for (int j = 0; j < 4; ++j) {
      bf16x4 t1, t3;
      t1[0] = (short)f2bf(v1[0][j]); t1[1] = (short)f2bf(v1[1][j]);
      t1[2] = (short)f2bf(v1[2][j]); t1[3] = (short)f2bf(v1[3][j]);
      t3[0] = (short)f2bf(v3[0][j]); t3[1] = (short)f2bf(v3[1][j]);
      t3[2] = (short)f2bf(v3[2][j]); t3[3] = (short)f2bf(v3[3][j]);
      *(bf16x4*)((char*)B1s[buf] + wBoff[j]) = t1;
      *(bf16x4*)((char*)B3s[buf] + wBoff[j]) = t3;
    }
  };

  LOAD(0); STORE(0);
  int cur = 0;
  const int NT = DD / BKR;
  for (int kt = 0; kt < NT; ++kt) {
    if (kt + 1 < NT) LOAD(kt + 1);
    __syncthreads();
    bf16x8 af[4];
#pragma unroll
    for (int m = 0; m < 4; ++m) af[m] = *(const bf16x8*)((const char*)As[cur] + aOff[m]);
#pragma unroll
    for (int n = 0; n < 4; ++n) {
      bf16x8 b1 = *(const bf16x8*)((const char*)B1s[cur] + bOff[n]);
      bf16x8 b3 = *(const bf16x8*)((const char*)B3s[cur] + bOff[n]);
#pragma unroll
      for (int m = 0; m < 4; ++m) {
        acc1[m][n] = __builtin_amdgcn_mfma_f32_16x16x32_bf16(af[m], b1, acc1[m][n], 0, 0, 0);
        acc3[m][n] = __builtin_amdgcn_mfma_f32_16x16x32_bf16(af[m], b3, acc3[m][n], 0, 0, 0);
      }
    }
    if (kt + 1 < NT) STORE(cur ^ 1);
    cur ^= 1;
  }

#pragma unroll
  for (int m = 0; m < 4; ++m) {
    const int rbase = wr * 64 + m * 16 + ((lane >> 4) << 2);
    float wts[4]; bool val[4];
#pragma unroll
    for (int j = 0; j < 4; ++j) {
      int r = m0 + rbase + j;
      val[j] = r < ce;
      wts[j] = val[j] ? lw[e * TK + r] : 0.f;
    }
#pragma unroll
    for (int n = 0; n < 4; ++n) {
      const int col = n0 + wc * 64 + n * 16 + (lane & 15);
#pragma unroll
      for (int j = 0; j < 4; ++j) {
        if (!val[j]) continue;
        float s1 = acc1[m][n][j], s3 = acc3[m][n][j];
        float h = s1 / (1.f + __expf(-s1)) * s3 * wts[j];
        H[(size_t)(base + m0 + rbase + j) * FF + col] = f2bf(h);
      }
    }
  }
}

__global__ __launch_bounds__(256, 2)
void k_gemm2(const unsigned short* __restrict__ H, const float* __restrict__ w2g,
             const int* __restrict__ cnt, const int* __restrict__ off,
             const int* __restrict__ ltok, float* __restrict__ out) {
  const int e = blockIdx.z;
  const int ce = cnt[e];
  const int m0 = blockIdx.y * BM;
  if (m0 >= ce) return;
  const int n0 = blockIdx.x * BN;
  const int tid = threadIdx.x, lane = tid & 63, wv = tid >> 6;
  const int wr = wv >> 1, wc = wv & 1;
  const float* W2 = w2g + (size_t)e * FF * DD;
  const int base = off[e];

  __shared__ unsigned short As[2][BM * BKR];
  __shared__ unsigned short Bs[2][BN * BKR];

  const int arow = tid >> 1, ah = tid & 1;
  const bool aval = (m0 + arow) < ce;
  const unsigned short* hrow = H + (size_t)(base + m0 + arow) * FF;
  const int kblk = tid >> 5, nblk = tid & 31;

  const int kb = (lane >> 4) * 16;
  int aOff[4], bOff[4], wAoff[2], wBoff[4];
#pragma unroll
  for (int m = 0; m < 4; ++m) aOff[m] = swzoff(wr * 64 + m * 16 + (lane & 15), kb);
#pragma unroll
  for (int n = 0; n < 4; ++n) bOff[n] = swzoff(permB(wc * 64 + n * 16 + (lane & 15)), kb);
#pragma unroll
  for (int j = 0; j < 2; ++j) wAoff[j] = swzoff(arow, ah * 32 + j * 16);
#pragma unroll
  for (int j = 0; j < 4; ++j) wBoff[j] = swzoff(permB(nblk * 4 + j), kblk * 8);

  f32x4 acc[4][4];
#pragma unroll
  for (int m = 0; m < 4; ++m)
#pragma unroll
    for (int n = 0; n < 4; ++n)
#pragma unroll
      for (int j = 0; j < 4; ++j) acc[m][n][j] = 0.f;

  bf16x8 av2[2];
  f32x4 wv2[4];

  auto LOAD = [&](int kt) {
    const int k0 = kt * BKR;
#pragma unroll
    for (int j = 0; j < 2; ++j) {
      if (aval) av2[j] = *(const bf16x8*)(hrow + k0 + ah * 16 + j * 8);
      else {
#pragma unroll
        for (int q = 0; q < 8; ++q) av2[j][q] = 0;
      }
    }
    const float* p = W2 + (size_t)(k0 + kblk * 4) * DD + (n0 + nblk * 4);
#pragma unroll
    for (int r = 0; r < 4; ++r) wv2[r] = *(const f32x4*)(p + (size_t)r * DD);
  };
  auto STORE = [&](int buf) {
#pragma unroll
    for (int j = 0; j < 2; ++j) *(bf16x8*)((char*)As[buf] + wAoff[j]) = av2[j];
#pragma unroll
    for (int j = 0; j < 4; ++j) {
      bf16x4 t;
      t[0] = (short)f2bf(wv2[0][j]); t[1] = (short)f2bf(wv2[1][j]);
      t[2] = (short)f2bf(wv2[2][j]); t[3] = (short)f2bf(wv2[3][j]);
      *(bf16x4*)((char*)Bs[buf] + wBoff[j]) = t;
    }
  };

  LOAD(0); STORE(0);
  int cur = 0;
  const int NT = FF / BKR;
  for (int kt = 0; kt < NT; ++kt) {
    if (kt + 1 < NT) LOAD(kt + 1);
    __syncthreads();
    bf16x8 af[4];
#pragma unroll
    for (int m = 0; m < 4; ++m) af[m] = *(const bf16x8*)((const char*)As[cur] + aOff[m]);
#pragma unroll
    for (int n = 0; n < 4; ++n) {
      bf16x8 bf = *(const bf16x8*)((const char*)Bs[cur] + bOff[n]);
#pragma unroll
      for (int m = 0; m < 4; ++m)
        acc[m][n] = __builtin_amdgcn_mfma_f32_16x16x32_bf16(af[m], bf, acc[m][n], 0, 0, 0);
    }
    if (kt + 1 < NT) STORE(cur ^ 1);
    cur ^= 1;
  }

#pragma unroll
  for (int m = 0; m < 4; ++m) {
    const int rbase = wr * 64 + m * 16 + ((lane >> 4) << 2);
    int toks[4]; bool val[4];
#pragma unroll
    for (int j = 0; j < 4; ++j) {
      int r = m0 + rbase + j;
      val[j] = r < ce;
      toks[j] = val[j] ? ltok[e * TK + r] : 0;
    }
#pragma unroll
    for (int n = 0; n < 4; ++n) {
      const int col = n0 + wc * 64 + n * 16 + (lane & 15);
#pragma unroll
      for (int j = 0; j < 4; ++j)
        if (val[j]) atomicAdd(out + (size_t)toks[j] * DD + col, acc[m][n][j]);
    }
  }
}

extern "C" void kernel_launch(void* const* d_in, const int* in_sizes, int n_in,
                              void* d_out, int out_size, void* d_ws, size_t ws_size,
                              hipStream_t stream) {
  const float* x  = (const float*)d_in[0];
  const float* gw = (const float*)d_in[1];
  const float* w1 = (const float*)d_in[2];
  const float* w3 = (const float*)d_in[3];
  const float* w2 = (const float*)d_in[4];
  float* out = (float*)d_out;

  char* ws = (char*)d_ws;
  int*   cnt  = (int*)(ws);
  int*   off  = (int*)(ws + 64);
  int*   ltok = (int*)(ws + 256);
  float* lw   = (float*)(ws + 256 + (size_t)NE * TK * 4);

  const size_t SZ_XB = (size_t)TK * DD * 2;        // 16.8 MB
  const size_t SZ_W  = (size_t)NE * DD * FF * 2;   // 134.2 MB
  const size_t SZ_H  = (size_t)2 * TK * FF * 2;    // 67.1 MB
  size_t o = (size_t)1 << 20;
  unsigned short* xb  = (unsigned short*)(ws + o); o += SZ_XB;
  unsigned short* w1t = (unsigned short*)(ws + o); o += SZ_W;
  unsigned short* w3t = (unsigned short*)(ws + o); o += SZ_W;
  unsigned short* w2t = (unsigned short*)(ws + o); o += SZ_W;
  unsigned short* Hg  = (unsigned short*)(ws + o); o += SZ_H;
  const bool full = (ws_size >= o);

  hipMemsetAsync(cnt, 0, 64, stream);
  hipMemsetAsync(d_out, 0, (size_t)out_size * 4, stream);

  if (full) {
    k_router<<<dim3(TK / 4), 256, 0, stream>>>(x, gw, cnt, ltok, lw, xb);
    k_prefix<<<dim3(1), 64, 0, stream>>>(cnt, off);
    k_tr<<<dim3(FF / 64, DD / 64, NE), 256, 0, stream>>>(w1, w1t, DD, FF);
    k_tr<<<dim3(FF / 64, DD / 64, NE), 256, 0, stream>>>(w3, w3t, DD, FF);
    k_tr<<<dim3(DD / 64, FF / 64, NE), 256, 0, stream>>>(w2, w2t, FF, DD);
    k_gemm1g<<<dim3(FF / BN, TK / BM, NE), 256, 0, stream>>>(xb, w1t, w3t, cnt, off, ltok, lw, Hg);
    k_gemm2g<<<dim3(DD / BN, TK / BM, NE), 256, 0, stream>>>(Hg, w2t, cnt, off, ltok, out);
  } else {
    unsigned short* H = (unsigned short*)(ws + ((size_t)1 << 20));
    if (ws_size < ((size_t)1 << 20) + SZ_H) return;
    k_router<<<dim3(TK / 4), 256, 0, stream>>>(x, gw, cnt, ltok, lw, (unsigned short*)nullptr);
    k_prefix<<<dim3(1), 64, 0, stream>>>(cnt, off);
    k_gemm1<<<dim3(FF / BN, TK / BM, NE), 256, 0, stream>>>(x, w1, w3, cnt, off, ltok, lw, H);
    k_gemm2<<<dim3(DD / BN, TK / BM, NE), 256, 0, stream>>>(H, w2, cnt, off, ltok, out);
  }
}